// Round 4
// baseline (443.347 us; speedup 1.0000x reference)
//
#include <hip/hip_runtime.h>

#define B_ 2
#define N_ 131072
#define K_ 20
#define E_ 256
#define TEMP_ 0.05f
#define SCORE_THR_ 0.04f

// ws layout (float offsets):
//   [0,40)              score[B][K]   (final mean scores, written by kC)
//   [1024,11264)        xn [B][K][E]
//   [16384,26624)       sn [B][K][E]
//   [32768,+B*K*N)      mask [B][K][N]            (ends at 5275648)
//   [6291456,+1024*20)  score partials per kB block
#define WS_SCORE 0
#define WS_XN    1024
#define WS_SN    16384
#define WS_MASK  32768
#define WS_SPART 6291456

__device__ inline float wave_sum(float v) {
    #pragma unroll
    for (int off = 32; off; off >>= 1) v += __shfl_xor(v, off, 64);
    return v;
}

// ---------------- Kernel A1: GEMM1 + GroupNorm + ReLU ----------------
__global__ __launch_bounds__(256) void kA1(const float* __restrict__ slots,
                                           const float* __restrict__ w1,
                                           const float* __restrict__ b1,
                                           const float* __restrict__ gn_g,
                                           const float* __restrict__ gn_b,
                                           float* __restrict__ ws) {
    __shared__ __align__(16) float slds[20 * 260];
    __shared__ float red[2];
    const int t = threadIdx.x;
    const int b = blockIdx.x >> 2, g = blockIdx.x & 3;
    if (t < 2) red[t] = 0.f;
    const float* sb = slots + (size_t)b * K_ * E_;
    #pragma unroll
    for (int i = 0; i < 20; ++i) slds[i * 260 + t] = sb[i * 256 + t];
    __syncthreads();

    const int c = t >> 2, q = t & 3;
    const int o = g * 64 + c;
    const float* w1r = w1 + (size_t)o * E_;
    float acc[5] = {0.f, 0.f, 0.f, 0.f, 0.f};
    for (int e4 = 0; e4 < 64; ++e4) {
        const float4 w4 = *(const float4*)(w1r + e4 * 4);
        #pragma unroll
        for (int kk = 0; kk < 5; ++kk) {
            const float4 s4 = *(const float4*)&slds[(q * 5 + kk) * 260 + e4 * 4];
            acc[kk] += w4.x * s4.x + w4.y * s4.y + w4.z * s4.z + w4.w * s4.w;
        }
    }
    const float bias = b1[o];
    float s1 = 0.f, s2 = 0.f;
    #pragma unroll
    for (int kk = 0; kk < 5; ++kk) {
        acc[kk] += bias;
        s1 += acc[kk];
        s2 += acc[kk] * acc[kk];
    }
    s1 = wave_sum(s1);
    s2 = wave_sum(s2);
    if ((t & 63) == 0) { atomicAdd(&red[0], s1); atomicAdd(&red[1], s2); }
    __syncthreads();
    const float mean = red[0] * (1.f / 1280.f);
    const float var  = red[1] * (1.f / 1280.f) - mean * mean;
    const float rstd = rsqrtf(var + 1e-5f);
    const float gg = gn_g[o], gb = gn_b[o];
    float* xn = ws + WS_XN + (size_t)b * K_ * E_;
    #pragma unroll
    for (int kk = 0; kk < 5; ++kk) {
        float v = (acc[kk] - mean) * rstd * gg + gb;
        v = v > 0.f ? v : 0.f;
        xn[(q * 5 + kk) * 256 + o] = v;
    }
}

// ---------------- Kernel A2: GEMM2 + bias + L2-normalize over E ----------------
__global__ __launch_bounds__(256) void kA2(const float* __restrict__ w2,
                                           const float* __restrict__ b2,
                                           float* __restrict__ ws) {
    __shared__ __align__(16) float xv[256];
    __shared__ float wred[4];
    const int t = threadIdx.x;
    const int b = blockIdx.x / 20, k = blockIdx.x % 20;
    const float* xn = ws + WS_XN + (size_t)(b * 20 + k) * 256;
    xv[t] = xn[t];
    __syncthreads();
    const float* w2r = w2 + (size_t)t * 256;
    float acc = 0.f;
    for (int e4 = 0; e4 < 64; ++e4) {
        const float4 w4 = *(const float4*)(w2r + e4 * 4);
        const float4 x4 = *(const float4*)&xv[e4 * 4];
        acc += w4.x * x4.x + w4.y * x4.y + w4.z * x4.z + w4.w * x4.w;
    }
    acc += b2[t];
    float sq = wave_sum(acc * acc);
    if ((t & 63) == 0) wred[t >> 6] = sq;
    __syncthreads();
    const float nsq = wred[0] + wred[1] + wred[2] + wred[3];
    const float inv = 1.f / fmaxf(sqrtf(nsq), 1e-12f);
    ws[WS_SN + (size_t)(b * 20 + k) * 256 + t] = acc * inv;
}

// ---------------- Kernel B v4: one point/thread, QUARTER-row staging (h=0..3) ----------------
// grid 1024 (512 blocks/batch, 256 points/block); 256 threads.
// Each pass h stages e in [64h, 64h+64) for all 256 points (coalesced 64KB),
// sn read with wave-uniform addresses (scalarizes to s_load / L1 broadcast).
// BUG FIX vs R3: h must run 0..3 (4 quarters of E=256), not 0..1.
__global__ __launch_bounds__(256, 2) void kB(const float* __restrict__ feat,
                                             const float* __restrict__ snb,
                                             float* __restrict__ mask,
                                             float* __restrict__ spart) {
    __shared__ __align__(16) float fl[256 * 68];
    __shared__ float wsum[4][20];
    const int t = threadIdx.x;
    const int b = blockIdx.x >> 9;
    const int n0 = (blockIdx.x & 511) << 8;

    const float4* g4 = (const float4*)(feat + ((size_t)b * N_ + n0) * E_);
    const float* snB = snb + (size_t)b * 5120;

    float acc[20];
    #pragma unroll
    for (int k = 0; k < 20; ++k) acc[k] = 0.f;
    float nr = 0.f;

    #pragma unroll
    for (int h = 0; h < 4; ++h) {   // 4 quarters x 64 floats = full E=256
        // ---- stage quarter-rows e in [64h, 64h+64) for all 256 points ----
        #pragma unroll
        for (int i = 0; i < 16; ++i) {
            const int f = (i << 8) + t;          // 0..4095
            const int p = f >> 4, e4 = f & 15;
            const float4 v = g4[(size_t)p * 64 + (h << 4) + e4];
            *(float4*)&fl[p * 68 + (e4 << 2)] = v;
        }
        __syncthreads();
        // ---- compute: thread t owns point t; sn loads are wave-uniform ----
        const float* frow = &fl[t * 68];
        for (int e4 = 0; e4 < 16; ++e4) {
            const float4 f4 = *(const float4*)&frow[e4 << 2];
            nr += f4.x * f4.x + f4.y * f4.y + f4.z * f4.z + f4.w * f4.w;
            const float* sp = snB + (h << 6) + (e4 << 2);
            #pragma unroll
            for (int k = 0; k < 20; ++k) {
                const float4 s4 = *(const float4*)&sp[k << 8];
                acc[k] += f4.x * s4.x + f4.y * s4.y + f4.z * s4.z + f4.w * s4.w;
            }
        }
        __syncthreads();   // fl reused by next quarter
    }

    // ---- softmax ----
    const float scl = rsqrtf(fmaxf(nr, 1e-24f)) * (1.f / TEMP_);
    float m = -1e30f;
    #pragma unroll
    for (int k = 0; k < 20; ++k) { acc[k] *= scl; m = fmaxf(m, acc[k]); }
    float su = 0.f;
    #pragma unroll
    for (int k = 0; k < 20; ++k) { acc[k] = __expf(acc[k] - m); su += acc[k]; }
    const float r = 1.f / su;

    // ---- store probs (coalesced dword per k) + score partials ----
    float* mg = mask + (size_t)b * 20 * N_ + n0 + t;
    #pragma unroll
    for (int k = 0; k < 20; ++k) {
        const float v = acc[k] * r;
        mg[(size_t)k * N_] = v;
        acc[k] = wave_sum(v);
    }
    const int lane = t & 63, w = t >> 6;
    if (lane < 20) {
        float v = 0.f;
        #pragma unroll
        for (int k = 0; k < 20; ++k) if (lane == k) v = acc[k];
        wsum[w][lane] = v;
    }
    __syncthreads();
    if (t < 20) {
        const float sum = wsum[0][t] + wsum[1][t] + wsum[2][t] + wsum[3][t];
        spart[(size_t)blockIdx.x * 20 + t] = sum;
    }
}

// ---------------- Kernel C: reduce score partials ----------------
__global__ __launch_bounds__(64) void kC(float* __restrict__ ws) {
    const int l = threadIdx.x;
    const int b = blockIdx.x / 20, k = blockIdx.x % 20;
    const float* sp = ws + WS_SPART;
    float sum = 0.f;
    #pragma unroll
    for (int i = 0; i < 8; ++i)
        sum += sp[(size_t)(b * 512 + l + i * 64) * 20 + k];
    sum = wave_sum(sum);
    if (l == 0) ws[WS_SCORE + blockIdx.x] = sum * (1.f / (float)N_);
}

// ---------------- Kernel D v2: rank/filter + gather + renormalize, float4 ----------------
// grid 256 (128 blocks/batch); 256 threads; 4 points/thread
__global__ __launch_bounds__(256) void kD(const float* __restrict__ ws,
                                          float* __restrict__ out) {
    __shared__ float sc[20];
    __shared__ int rnk[20];
    __shared__ int src[20];
    __shared__ int nk_s;
    const int t = threadIdx.x;
    const int b = blockIdx.x >> 7;
    const int n = ((blockIdx.x & 127) << 10) + (t << 2);
    if (t < 20) sc[t] = ws[WS_SCORE + b * 20 + t];
    if (t == 0) nk_s = 0;
    __syncthreads();
    if (t < 20) {
        const float mys = sc[t];
        int rank = 0;
        for (int j = 0; j < 20; ++j) {
            const float o = sc[j];
            rank += (o > mys) || (o == mys && j < t);
        }
        rnk[t] = rank;
    }
    __syncthreads();
    if (t < 20 && sc[t] >= SCORE_THR_) {
        int pos = 0;
        for (int j = 0; j < 20; ++j)
            pos += (sc[j] >= SCORE_THR_) && (rnk[j] < rnk[t]);
        src[pos] = t;
        atomicAdd(&nk_s, 1);
    }
    __syncthreads();
    const int nk = nk_s;
    const float* mg = ws + WS_MASK + (size_t)b * 20 * N_;
    float4 mv[20];
    float4 den = {1e-8f, 1e-8f, 1e-8f, 1e-8f};
    #pragma unroll
    for (int p = 0; p < 20; ++p) {
        float4 v = {0.f, 0.f, 0.f, 0.f};
        if (p < nk) v = *(const float4*)&mg[(size_t)src[p] * N_ + n];
        mv[p] = v;
        den.x += v.x; den.y += v.y; den.z += v.z; den.w += v.w;
    }
    const float4 r = {1.f / den.x, 1.f / den.y, 1.f / den.z, 1.f / den.w};
    float* og = out + (size_t)b * 20 * N_ + n;
    #pragma unroll
    for (int p = 0; p < 20; ++p) {
        float4 o4 = {0.f, 0.f, 0.f, 0.f};
        if (p < nk) {
            o4.x = mv[p].x * r.x; o4.y = mv[p].y * r.y;
            o4.z = mv[p].z * r.z; o4.w = mv[p].w * r.w;
        }
        *(float4*)&og[(size_t)p * N_] = o4;
    }
}

extern "C" void kernel_launch(void* const* d_in, const int* in_sizes, int n_in,
                              void* d_out, int out_size, void* d_ws, size_t ws_size,
                              hipStream_t stream) {
    const float* feat  = (const float*)d_in[0];
    const float* slots = (const float*)d_in[1];
    const float* w1    = (const float*)d_in[2];
    const float* b1    = (const float*)d_in[3];
    const float* gng   = (const float*)d_in[4];
    const float* gnb   = (const float*)d_in[5];
    const float* w2    = (const float*)d_in[6];
    const float* b2    = (const float*)d_in[7];
    float* ws  = (float*)d_ws;
    float* out = (float*)d_out;

    kA1<<<8,    256, 0, stream>>>(slots, w1, b1, gng, gnb, ws);
    kA2<<<40,   256, 0, stream>>>(w2, b2, ws);
    kB <<<1024, 256, 0, stream>>>(feat, ws + WS_SN, ws + WS_MASK, ws + WS_SPART);
    kC <<<40,   64,  0, stream>>>(ws);
    kD <<<256,  256, 0, stream>>>(ws, out);
}